// Round 1
// baseline (391.324 us; speedup 1.0000x reference)
//
#include <hip/hip_runtime.h>
#include <hip/hip_bf16.h>

#define DIM 768
#define TTOK 32
#define NTOK 32768

typedef __attribute__((ext_vector_type(8))) short short8;
typedef __attribute__((ext_vector_type(4))) float f32x4;

__device__ __forceinline__ unsigned short f2bf(float f) {
  union { float f; unsigned int u; } v; v.f = f;
  unsigned int u = v.u;
  return (unsigned short)((u + 0x7fffu + ((u >> 16) & 1u)) >> 16);
}

__global__ void bucket_kernel(const int* __restrict__ mask,
                              int* __restrict__ counts, int* __restrict__ lists) {
  int i = blockIdx.x * 256 + threadIdx.x;
  if (i < NTOK) {
    int e = mask[i] & 3;
    int pos = atomicAdd(&counts[e], 1);
    lists[e * NTOK + pos] = i;
  }
}

__global__ void prep_kernel(const float* __restrict__ Wd0, const float* __restrict__ Wd1,
                            const float* __restrict__ Wd2, const float* __restrict__ Wd3,
                            const float* __restrict__ Wu0, const float* __restrict__ Wu1,
                            const float* __restrict__ Wu2, const float* __restrict__ Wu3,
                            unsigned short* __restrict__ wdT, unsigned short* __restrict__ wuT) {
  int e = blockIdx.x;
  int ds = 16 << e;
  int KP = (e == 0) ? 32 : ds;
  const float* Wd = (e == 0) ? Wd0 : (e == 1) ? Wd1 : (e == 2) ? Wd2 : Wd3;
  const float* Wu = (e == 0) ? Wu0 : (e == 1) ? Wu1 : (e == 2) ? Wu2 : Wu3;
  const int WOFF[4] = {0, 12288, 36864, 86016};
  const int UOFF[4] = {0, 24576, 49152, 98304};
  int stride = gridDim.y * 256;
  int start = blockIdx.y * 256 + threadIdx.x;
  int nd = ds * DIM;
  for (int i = start; i < nd; i += stride) {
    int k = i / DIM, d = i - k * DIM;   // wdT layout [ds][768]
    wdT[WOFF[e] + i] = f2bf(Wd[d * ds + k]);
  }
  int nu = DIM * KP;
  for (int i = start; i < nu; i += stride) {
    int dc = i / KP, k = i - dc * KP;   // wuT layout [768][KP], zero-pad k>=ds
    wuT[UOFF[e] + i] = (k < ds) ? f2bf(Wu[k * DIM + dc]) : (unsigned short)0;
  }
}

__global__ __launch_bounds__(256, 2) void moe_main(
    const float* __restrict__ x,
    const int* __restrict__ counts, const int* __restrict__ lists,
    const unsigned short* __restrict__ wdT, const unsigned short* __restrict__ wuT,
    const float* __restrict__ bd0, const float* __restrict__ bd1,
    const float* __restrict__ bd2, const float* __restrict__ bd3,
    const float* __restrict__ bu0, const float* __restrict__ bu1,
    const float* __restrict__ bu2, const float* __restrict__ bu3,
    float* __restrict__ out)
{
  int e = blockIdx.x & 3;
  int tile = blockIdx.x >> 2;
  int cnt = counts[e];
  int base = tile * TTOK;
  if (base >= cnt) return;
  int nt = min(TTOK, cnt - base);
  int ds = 16 << e;
  int KP = (e == 0) ? 32 : ds;
  const int WOFF[4] = {0, 12288, 36864, 86016};
  const int UOFF[4] = {0, 24576, 49152, 98304};
  const unsigned short* wd = wdT + WOFF[e];
  const unsigned short* wu = wuT + UOFF[e];
  const float* bdp = (e == 0) ? bd0 : (e == 1) ? bd1 : (e == 2) ? bd2 : bd3;
  const float* bup = (e == 0) ? bu0 : (e == 1) ? bu1 : (e == 2) ? bu2 : bu3;

  __shared__ int toks[TTOK];
  __shared__ unsigned short xs[TTOK][776];   // bf16 x tile, +8 pad
  __shared__ unsigned short dn[TTOK][136];   // bf16 down tile, +8 pad

  int tid = threadIdx.x;
  if (tid < TTOK) {
    int t = -1;
    if (tid < nt) t = lists[e * NTOK + base + tid];
    toks[tid] = t;
  }
  for (int i = tid; i < TTOK * 136; i += 256) ((unsigned short*)dn)[i] = 0;
  __syncthreads();

  // ---- stage x tile -> LDS bf16 ----
  {
    int r = tid >> 3, j = tid & 7;   // 8 threads per row
    int t = toks[r];
    const float4* src = (t >= 0) ? (const float4*)(x + (size_t)t * DIM) : nullptr;
    #pragma unroll 4
    for (int c = 0; c < 24; ++c) {
      int f4 = c * 8 + j;
      float4 v;
      if (src) v = src[f4]; else { v.x = v.y = v.z = v.w = 0.f; }
      ushort4 b;
      b.x = f2bf(v.x); b.y = f2bf(v.y); b.z = f2bf(v.z); b.w = f2bf(v.w);
      *(ushort4*)&xs[r][f4 * 4] = b;
    }
  }
  __syncthreads();

  int wv = tid >> 6, lane = tid & 63;
  int lrow = lane & 15, kg = lane >> 4;

  // ---- phase A: down = relu(X @ Wd + bd) ----
  int ntile = ds >> 4;
  int nitemsA = 2 * ntile;
  for (int item = wv; item < nitemsA; item += 4) {
    int m = item & 1, n = item >> 1;
    f32x4 acc = {0.f, 0.f, 0.f, 0.f};
    const unsigned short* xrow = &xs[m * 16 + lrow][kg * 8];
    const unsigned short* wrow = wd + (size_t)(n * 16 + lrow) * DIM + kg * 8;
    #pragma unroll 4
    for (int d0 = 0; d0 < DIM; d0 += 32) {
      short8 a = *(const short8*)(xrow + d0);
      short8 b = *(const short8*)(wrow + d0);
      acc = __builtin_amdgcn_mfma_f32_16x16x32_bf16(a, b, acc, 0, 0, 0);
    }
    int kcol = n * 16 + lrow;
    float bv = bdp[kcol];
    #pragma unroll
    for (int r = 0; r < 4; ++r) {
      int t = m * 16 + kg * 4 + r;
      float v = acc[r] + bv;
      v = fmaxf(v, 0.f);
      dn[t][kcol] = f2bf(v);
    }
  }
  __syncthreads();

  // ---- phase B: up = dn @ Wu + bu + x ----
  for (int item = wv; item < 96; item += 4) {
    int m = item & 1, n = item >> 1;   // n: 0..47 dcol tiles
    f32x4 acc = {0.f, 0.f, 0.f, 0.f};
    const unsigned short* arow = &dn[m * 16 + lrow][kg * 8];
    const unsigned short* brow = wu + (size_t)(n * 16 + lrow) * KP + kg * 8;
    for (int k0 = 0; k0 < KP; k0 += 32) {
      short8 a = *(const short8*)(arow + k0);
      short8 b = *(const short8*)(brow + k0);
      acc = __builtin_amdgcn_mfma_f32_16x16x32_bf16(a, b, acc, 0, 0, 0);
    }
    int dcol = n * 16 + lrow;
    float bv = bup[dcol];
    #pragma unroll
    for (int r = 0; r < 4; ++r) {
      int t = m * 16 + kg * 4 + r;
      if (t < nt) {
        int tok = toks[t];
        float xr = __uint_as_float((unsigned int)xs[t][dcol] << 16);
        out[(size_t)tok * DIM + dcol] = acc[r] + bv + xr;
      }
    }
  }
}

extern "C" void kernel_launch(void* const* d_in, const int* in_sizes, int n_in,
                              void* d_out, int out_size, void* d_ws, size_t ws_size,
                              hipStream_t stream) {
  const float* x = (const float*)d_in[0];
  const int* mask = (const int*)d_in[1];
  const float* Wd[4]; const float* bd[4]; const float* Wu[4]; const float* bu[4];
  for (int i = 0; i < 4; ++i) {
    Wd[i] = (const float*)d_in[2 + 4 * i];
    bd[i] = (const float*)d_in[3 + 4 * i];
    Wu[i] = (const float*)d_in[4 + 4 * i];
    bu[i] = (const float*)d_in[5 + 4 * i];
  }
  char* ws = (char*)d_ws;
  int* counts = (int*)ws;                                   // 16 B
  int* lists = (int*)(ws + 256);                            // 4*32768*4 = 524288 B
  unsigned short* wdT = (unsigned short*)(ws + 256 + 524288);          // 368640 B
  unsigned short* wuT = (unsigned short*)(ws + 256 + 524288 + 368640); // 393216 B

  hipMemsetAsync(counts, 0, 16, stream);
  bucket_kernel<<<128, 256, 0, stream>>>(mask, counts, lists);
  prep_kernel<<<dim3(4, 32), 256, 0, stream>>>(Wd[0], Wd[1], Wd[2], Wd[3],
                                               Wu[0], Wu[1], Wu[2], Wu[3], wdT, wuT);
  moe_main<<<4096, 256, 0, stream>>>(x, counts, lists, wdT, wuT,
                                     bd[0], bd[1], bd[2], bd[3],
                                     bu[0], bu[1], bu[2], bu[3],
                                     (float*)d_out);
}

// Round 2
// 143.596 us; speedup vs baseline: 2.7252x; 2.7252x over previous
//
#include <hip/hip_runtime.h>
#include <hip/hip_bf16.h>

#define DIM 768
#define NTOK 32768

typedef __attribute__((ext_vector_type(8))) short short8;
typedef __attribute__((ext_vector_type(4))) float f32x4;

__device__ __forceinline__ unsigned short f2bf(float f) {
  union { float f; unsigned int u; } v; v.f = f;
  unsigned int u = v.u;
  return (unsigned short)((u + 0x7fffu + ((u >> 16) & 1u)) >> 16);
}

// ---- two-level bucketing: ballot rank -> LDS wave prefix -> 4 atomics/block
__global__ void bucket_kernel(const int* __restrict__ mask,
                              int* __restrict__ counts, int* __restrict__ lists) {
  int tid = threadIdx.x;
  int gid = blockIdx.x * 256 + tid;
  int wv = tid >> 6, lane = tid & 63;
  int e = mask[gid] & 3;
  __shared__ int wcnt[4][4];   // [wave][expert]
  __shared__ int wbase[4][4];
  __shared__ int bbase[4];
  unsigned long long lt = (1ull << lane) - 1ull;
  int rank = 0;
  #pragma unroll
  for (int q = 0; q < 4; ++q) {
    unsigned long long m = __ballot(e == q);
    if (e == q) rank = __popcll(m & lt);
    if (lane == 0) wcnt[wv][q] = __popcll(m);
  }
  __syncthreads();
  if (tid < 4) {
    int s = 0;
    #pragma unroll
    for (int w2 = 0; w2 < 4; ++w2) { int c = wcnt[w2][tid]; wbase[w2][tid] = s; s += c; }
    bbase[tid] = atomicAdd(&counts[tid], s);
  }
  __syncthreads();
  int pos = bbase[e] + wbase[wv][e] + rank;
  lists[e * NTOK + pos] = gid;
}

// ---- weight repack to bf16 (WdT [ds][768], WuT [768][KP] zero-padded) + tileStart
__global__ void prep_kernel(const float* __restrict__ Wd0, const float* __restrict__ Wd1,
                            const float* __restrict__ Wd2, const float* __restrict__ Wd3,
                            const float* __restrict__ Wu0, const float* __restrict__ Wu1,
                            const float* __restrict__ Wu2, const float* __restrict__ Wu3,
                            unsigned short* __restrict__ wdT, unsigned short* __restrict__ wuT,
                            int* __restrict__ counts) {
  int e = blockIdx.x;
  int ds = 16 << e;
  int lgK = (e == 0) ? 5 : (4 + e);
  int KP = 1 << lgK;
  const float* Wd = (e == 0) ? Wd0 : (e == 1) ? Wd1 : (e == 2) ? Wd2 : Wd3;
  const float* Wu = (e == 0) ? Wu0 : (e == 1) ? Wu1 : (e == 2) ? Wu2 : Wu3;
  const int WOFF[4] = {0, 12288, 36864, 86016};
  const int UOFF[4] = {0, 24576, 49152, 98304};
  int stride = gridDim.y * 256;
  int start = blockIdx.y * 256 + threadIdx.x;
  int nd = ds * DIM;
  for (int i = start; i < nd; i += stride) {
    int k = i / DIM, d = i - k * DIM;
    wdT[WOFF[e] + i] = f2bf(Wd[d * ds + k]);
  }
  int nu = DIM << lgK;
  for (int i = start; i < nu; i += stride) {
    int dc = i >> lgK, k = i & (KP - 1);
    wuT[UOFF[e] + i] = (k < ds) ? f2bf(Wu[k * DIM + dc]) : (unsigned short)0;
  }
  if (e == 0 && blockIdx.y == 0 && threadIdx.x == 0) {
    int* ts = counts + 8;
    int s = 0;
    for (int q = 0; q < 4; ++q) { ts[q] = s; s += (counts[q] + 15) >> 4; }
    ts[4] = s;
  }
}

// ---- per-wave 16-token tile, templated expert, no barriers
template <int E>
__device__ __forceinline__ void moe_body(
    int wv, int lane, int tile, int cnt,
    const float* __restrict__ x, const int* __restrict__ lists,
    const unsigned short* __restrict__ wdT, const unsigned short* __restrict__ wuT,
    const float* __restrict__ bd, const float* __restrict__ bu,
    float* __restrict__ out,
    unsigned short (*dnw)[16][136], int (*tokw)[16]) {
  constexpr int DS = 16 << E;
  constexpr int KP = (E == 0) ? 32 : DS;
  constexpr int NTA = DS / 16;
  constexpr int KB = KP / 32;
  constexpr int WOFF[4] = {0, 12288, 36864, 86016};
  constexpr int UOFF[4] = {0, 24576, 49152, 98304};
  const unsigned short* wd = wdT + WOFF[E];
  const unsigned short* wu = wuT + UOFF[E];

  int base = tile * 16;
  int lrow = lane & 15, kg = lane >> 4;
  if (lane < 16) tokw[wv][lane] = (base + lane < cnt) ? lists[E * NTOK + base + lane] : -1;
  int t = tokw[wv][lrow];
  bool valid = t >= 0;
  const float* xrow = x + (size_t)(valid ? t : 0) * DIM + kg * 8;

  f32x4 acc[NTA];
  #pragma unroll
  for (int n = 0; n < NTA; ++n) acc[n] = f32x4{0.f, 0.f, 0.f, 0.f};

  constexpr int UF = (E >= 2) ? 2 : 4;
  for (int d0 = 0; d0 < DIM; d0 += 32 * UF) {
    #pragma unroll
    for (int u = 0; u < UF; ++u) {
      int d = d0 + u * 32;
      float4 v0 = {0.f, 0.f, 0.f, 0.f}, v1 = {0.f, 0.f, 0.f, 0.f};
      if (valid) { v0 = *(const float4*)(xrow + d); v1 = *(const float4*)(xrow + d + 4); }
      short8 a;
      a[0] = (short)f2bf(v0.x); a[1] = (short)f2bf(v0.y);
      a[2] = (short)f2bf(v0.z); a[3] = (short)f2bf(v0.w);
      a[4] = (short)f2bf(v1.x); a[5] = (short)f2bf(v1.y);
      a[6] = (short)f2bf(v1.z); a[7] = (short)f2bf(v1.w);
      #pragma unroll
      for (int n = 0; n < NTA; ++n) {
        short8 b = *(const short8*)(wd + (size_t)(n * 16 + lrow) * DIM + d + kg * 8);
        acc[n] = __builtin_amdgcn_mfma_f32_16x16x32_bf16(a, b, acc[n], 0, 0, 0);
      }
    }
  }

  // relu + bias -> per-wave LDS transpose buffer (bf16)
  #pragma unroll
  for (int n = 0; n < NTA; ++n) {
    float bv = bd[n * 16 + lrow];
    #pragma unroll
    for (int r = 0; r < 4; ++r) {
      float v = fmaxf(acc[n][r] + bv, 0.f);
      dnw[wv][kg * 4 + r][n * 16 + lrow] = f2bf(v);
    }
  }
  if (E == 0) {  // zero the k-pad so padded Wu rows can't meet garbage
    #pragma unroll
    for (int r = 0; r < 4; ++r) dnw[wv][kg * 4 + r][16 + lrow] = 0;
  }

  // phase B: up = dn @ Wu + bu + x  (A-frag hoisted, loop-invariant in n)
  short8 afr[KB];
  #pragma unroll
  for (int k = 0; k < KB; ++k) afr[k] = *(const short8*)&dnw[wv][lrow][k * 32 + kg * 8];
  int trow[4];
  #pragma unroll
  for (int r = 0; r < 4; ++r) trow[r] = tokw[wv][kg * 4 + r];

  #pragma unroll 4
  for (int n = 0; n < 48; ++n) {
    f32x4 c = {0.f, 0.f, 0.f, 0.f};
    #pragma unroll
    for (int k = 0; k < KB; ++k) {
      short8 b = *(const short8*)(wu + (size_t)(n * 16 + lrow) * KP + k * 32 + kg * 8);
      c = __builtin_amdgcn_mfma_f32_16x16x32_bf16(afr[k], b, c, 0, 0, 0);
    }
    int dcol = n * 16 + lrow;
    float bv = bu[dcol];
    #pragma unroll
    for (int r = 0; r < 4; ++r) {
      int tr = trow[r];
      if (tr >= 0) {
        size_t o = (size_t)tr * DIM + dcol;
        out[o] = c[r] + bv + x[o];
      }
    }
  }
}

__global__ __launch_bounds__(256, 4) void moe_main(
    const float* __restrict__ x,
    const int* __restrict__ cw, const int* __restrict__ lists,
    const unsigned short* __restrict__ wdT, const unsigned short* __restrict__ wuT,
    const float* __restrict__ bd0, const float* __restrict__ bd1,
    const float* __restrict__ bd2, const float* __restrict__ bd3,
    const float* __restrict__ bu0, const float* __restrict__ bu1,
    const float* __restrict__ bu2, const float* __restrict__ bu3,
    float* __restrict__ out) {
  __shared__ unsigned short dnw[4][16][136];
  __shared__ int tokw[4][16];
  int tid = threadIdx.x, wv = tid >> 6, lane = tid & 63;
  int w = blockIdx.x * 4 + wv;
  const int* ts = cw + 8;
  if (w >= ts[4]) return;
  int e = (w >= ts[2]) ? ((w >= ts[3]) ? 3 : 2) : ((w >= ts[1]) ? 1 : 0);
  int tile = w - ts[e];
  int cnt = cw[e];
  if (e == 0)
    moe_body<0>(wv, lane, tile, cnt, x, lists, wdT, wuT, bd0, bu0, out, dnw, tokw);
  else if (e == 1)
    moe_body<1>(wv, lane, tile, cnt, x, lists, wdT, wuT, bd1, bu1, out, dnw, tokw);
  else if (e == 2)
    moe_body<2>(wv, lane, tile, cnt, x, lists, wdT, wuT, bd2, bu2, out, dnw, tokw);
  else
    moe_body<3>(wv, lane, tile, cnt, x, lists, wdT, wuT, bd3, bu3, out, dnw, tokw);
}

extern "C" void kernel_launch(void* const* d_in, const int* in_sizes, int n_in,
                              void* d_out, int out_size, void* d_ws, size_t ws_size,
                              hipStream_t stream) {
  const float* x = (const float*)d_in[0];
  const int* mask = (const int*)d_in[1];
  const float* Wd[4]; const float* bd[4]; const float* Wu[4]; const float* bu[4];
  for (int i = 0; i < 4; ++i) {
    Wd[i] = (const float*)d_in[2 + 4 * i];
    bd[i] = (const float*)d_in[3 + 4 * i];
    Wu[i] = (const float*)d_in[4 + 4 * i];
    bu[i] = (const float*)d_in[5 + 4 * i];
  }
  char* ws = (char*)d_ws;
  int* counts = (int*)ws;                                              // 64 B (counts + tileStart)
  int* lists = (int*)(ws + 256);                                       // 524288 B
  unsigned short* wdT = (unsigned short*)(ws + 256 + 524288);          // 368640 B
  unsigned short* wuT = (unsigned short*)(ws + 256 + 524288 + 368640); // 393216 B

  hipMemsetAsync(counts, 0, 64, stream);
  bucket_kernel<<<128, 256, 0, stream>>>(mask, counts, lists);
  prep_kernel<<<dim3(4, 32), 256, 0, stream>>>(Wd[0], Wd[1], Wd[2], Wd[3],
                                               Wu[0], Wu[1], Wu[2], Wu[3], wdT, wuT, counts);
  // Sum of per-expert tiles is at most 32768/16 + 3 = 2051 waves -> 513 blocks.
  moe_main<<<513, 256, 0, stream>>>(x, counts, lists, wdT, wuT,
                                    bd[0], bd[1], bd[2], bd[3],
                                    bu[0], bu[1], bu[2], bu[3],
                                    (float*)d_out);
}

// Round 3
// 121.008 us; speedup vs baseline: 3.2339x; 1.1867x over previous
//
#include <hip/hip_runtime.h>
#include <hip/hip_bf16.h>

#define DIM 768
#define NTOK 32768
#define TTOK 16

typedef __attribute__((ext_vector_type(8))) short short8;
typedef __attribute__((ext_vector_type(4))) float f32x4;

__device__ __forceinline__ unsigned short f2bf(float f) {
  union { float f; unsigned int u; } v; v.f = f;
  unsigned int u = v.u;
  return (unsigned short)((u + 0x7fffu + ((u >> 16) & 1u)) >> 16);
}

// ---- two-level bucketing: ballot rank -> LDS wave prefix -> 4 atomics/block
__global__ void bucket_kernel(const int* __restrict__ mask,
                              int* __restrict__ counts, int* __restrict__ lists) {
  int tid = threadIdx.x;
  int gid = blockIdx.x * 256 + tid;
  int wv = tid >> 6, lane = tid & 63;
  int e = mask[gid] & 3;
  __shared__ int wcnt[4][4];
  __shared__ int wbase[4][4];
  __shared__ int bbase[4];
  unsigned long long lt = (1ull << lane) - 1ull;
  int rank = 0;
  #pragma unroll
  for (int q = 0; q < 4; ++q) {
    unsigned long long m = __ballot(e == q);
    if (e == q) rank = __popcll(m & lt);
    if (lane == 0) wcnt[wv][q] = __popcll(m);
  }
  __syncthreads();
  if (tid < 4) {
    int s = 0;
    #pragma unroll
    for (int w2 = 0; w2 < 4; ++w2) { int c = wcnt[w2][tid]; wbase[w2][tid] = s; s += c; }
    bbase[tid] = atomicAdd(&counts[tid], s);
  }
  __syncthreads();
  int pos = bbase[e] + wbase[wv][e] + rank;
  lists[e * NTOK + pos] = gid;
}

// ---- weight repack to bf16 (WdT [ds][768], WuT [768][KP] zero-padded) + tileStart
__global__ void prep_kernel(const float* __restrict__ Wd0, const float* __restrict__ Wd1,
                            const float* __restrict__ Wd2, const float* __restrict__ Wd3,
                            const float* __restrict__ Wu0, const float* __restrict__ Wu1,
                            const float* __restrict__ Wu2, const float* __restrict__ Wu3,
                            unsigned short* __restrict__ wdT, unsigned short* __restrict__ wuT,
                            int* __restrict__ counts) {
  int e = blockIdx.x;
  int ds = 16 << e;
  int lgK = (e == 0) ? 5 : (4 + e);
  int KP = 1 << lgK;
  const float* Wd = (e == 0) ? Wd0 : (e == 1) ? Wd1 : (e == 2) ? Wd2 : Wd3;
  const float* Wu = (e == 0) ? Wu0 : (e == 1) ? Wu1 : (e == 2) ? Wu2 : Wu3;
  const int WOFF[4] = {0, 12288, 36864, 86016};
  const int UOFF[4] = {0, 24576, 49152, 98304};
  int stride = gridDim.y * 256;
  int start = blockIdx.y * 256 + threadIdx.x;
  int nd = ds * DIM;
  for (int i = start; i < nd; i += stride) {
    int k = i / DIM, d = i - k * DIM;
    wdT[WOFF[e] + i] = f2bf(Wd[d * ds + k]);
  }
  int nu = DIM << lgK;
  for (int i = start; i < nu; i += stride) {
    int dc = i >> lgK, k = i & (KP - 1);
    wuT[UOFF[e] + i] = (k < ds) ? f2bf(Wu[k * DIM + dc]) : (unsigned short)0;
  }
  if (e == 0 && blockIdx.y == 0 && threadIdx.x == 0) {
    int* ts = counts + 8;
    int s = 0;
    for (int q = 0; q < 4; ++q) { ts[q] = s; s += (counts[q] + 15) >> 4; }
    ts[4] = s;
  }
}

// ---- block-cooperative 16-token tile: 4 waves split phase A (K or n-tiles)
// and phase B (dcol quarters). Residual reads land in the same wave's L1.
template <int E>
__device__ __forceinline__ void moe_body(
    int wv, int lane, int tid, int tile, int cnt,
    const float* __restrict__ x, const int* __restrict__ lists,
    const unsigned short* __restrict__ wdT, const unsigned short* __restrict__ wuT,
    const float* __restrict__ bd, const float* __restrict__ bu,
    float* __restrict__ out,
    float* dnpart, unsigned short (*dn)[136], int* toks) {
  constexpr int DS = 16 << E;
  constexpr int KP = (E == 0) ? 32 : DS;
  constexpr int NTA = DS / 16;
  constexpr int SPLIT_N = (NTA < 4) ? NTA : 4;   // 1,2,4,4
  constexpr int SPLIT_K = 4 / SPLIT_N;           // 4,2,1,1
  constexpr int NTB = NTA / SPLIT_N;             // 1,1,1,2
  constexpr int KLEN = DIM / SPLIT_K;            // 192,384,768,768
  constexpr int KB = KP / 32;                    // 1,1,2,4
  constexpr int WOFF[4] = {0, 12288, 36864, 86016};
  constexpr int UOFF[4] = {0, 24576, 49152, 98304};
  const unsigned short* wd = wdT + WOFF[E];
  const unsigned short* wu = wuT + UOFF[E];

  int base = tile * TTOK;
  int lrow = lane & 15, kg = lane >> 4;
  if (tid < TTOK) toks[tid] = (base + tid < cnt) ? lists[E * NTOK + base + tid] : -1;
  if (SPLIT_K > 1) {
    for (int i = tid; i < TTOK * DS; i += 256) dnpart[i] = 0.f;
  }
  __syncthreads();

  int nsub = wv % SPLIT_N, ksub = wv / SPLIT_N;
  int d_base = ksub * KLEN;

  int t = toks[lrow];
  bool valid = t >= 0;
  const float* xrow = x + (size_t)(valid ? t : 0) * DIM + d_base + kg * 8;

  f32x4 acc[NTB];
  #pragma unroll
  for (int nb = 0; nb < NTB; ++nb) acc[nb] = f32x4{0.f, 0.f, 0.f, 0.f};

  for (int d0 = 0; d0 < KLEN; d0 += 64) {
    #pragma unroll
    for (int u = 0; u < 2; ++u) {
      int d = d0 + u * 32;
      float4 v0 = {0.f, 0.f, 0.f, 0.f}, v1 = {0.f, 0.f, 0.f, 0.f};
      if (valid) { v0 = *(const float4*)(xrow + d); v1 = *(const float4*)(xrow + d + 4); }
      short8 a;
      a[0] = (short)f2bf(v0.x); a[1] = (short)f2bf(v0.y);
      a[2] = (short)f2bf(v0.z); a[3] = (short)f2bf(v0.w);
      a[4] = (short)f2bf(v1.x); a[5] = (short)f2bf(v1.y);
      a[6] = (short)f2bf(v1.z); a[7] = (short)f2bf(v1.w);
      #pragma unroll
      for (int nb = 0; nb < NTB; ++nb) {
        int n = nsub * NTB + nb;
        short8 b = *(const short8*)(wd + (size_t)(n * 16 + lrow) * DIM + d_base + d + kg * 8);
        acc[nb] = __builtin_amdgcn_mfma_f32_16x16x32_bf16(a, b, acc[nb], 0, 0, 0);
      }
    }
  }

  if (SPLIT_K > 1) {
    // partial-K: combine via LDS f32 atomics, then reduce+relu+bias
    #pragma unroll
    for (int nb = 0; nb < NTB; ++nb) {
      int kc = (nsub * NTB + nb) * 16 + lrow;
      #pragma unroll
      for (int r = 0; r < 4; ++r)
        atomicAdd(&dnpart[(kg * 4 + r) * DS + kc], acc[nb][r]);
    }
    __syncthreads();
    for (int i = tid; i < TTOK * KP; i += 256) {
      int tt = i / KP, k = i - tt * KP;
      float v = (k < DS) ? fmaxf(dnpart[tt * DS + k] + bd[k], 0.f) : 0.f;
      dn[tt][k] = f2bf(v);
    }
  } else {
    // exclusive n-tiles: write dn directly
    #pragma unroll
    for (int nb = 0; nb < NTB; ++nb) {
      int kc = (nsub * NTB + nb) * 16 + lrow;
      float bv = bd[kc];
      #pragma unroll
      for (int r = 0; r < 4; ++r)
        dn[kg * 4 + r][kc] = f2bf(fmaxf(acc[nb][r] + bv, 0.f));
    }
  }
  __syncthreads();

  // ---- phase B: wave wv owns dcol in [192*wv, 192*wv+192)
  short8 afr[KB];
  #pragma unroll
  for (int k = 0; k < KB; ++k) afr[k] = *(const short8*)&dn[lrow][k * 32 + kg * 8];
  int trow[4];
  #pragma unroll
  for (int r = 0; r < 4; ++r) trow[r] = toks[kg * 4 + r];

  #pragma unroll 3
  for (int nn = 0; nn < 12; ++nn) {
    int n = wv * 12 + nn;
    f32x4 c = {0.f, 0.f, 0.f, 0.f};
    #pragma unroll
    for (int k = 0; k < KB; ++k) {
      short8 b = *(const short8*)(wu + (size_t)(n * 16 + lrow) * KP + k * 32 + kg * 8);
      c = __builtin_amdgcn_mfma_f32_16x16x32_bf16(afr[k], b, c, 0, 0, 0);
    }
    int dcol = n * 16 + lrow;
    float bv = bu[dcol];
    #pragma unroll
    for (int r = 0; r < 4; ++r) {
      int tr = trow[r];
      if (tr >= 0) {
        size_t o = (size_t)tr * DIM + dcol;
        out[o] = c[r] + bv + x[o];
      }
    }
  }
}

__global__ __launch_bounds__(256, 6) void moe_main(
    const float* __restrict__ x,
    const int* __restrict__ cw, const int* __restrict__ lists,
    const unsigned short* __restrict__ wdT, const unsigned short* __restrict__ wuT,
    const float* __restrict__ bd0, const float* __restrict__ bd1,
    const float* __restrict__ bd2, const float* __restrict__ bd3,
    const float* __restrict__ bu0, const float* __restrict__ bu1,
    const float* __restrict__ bu2, const float* __restrict__ bu3,
    float* __restrict__ out) {
  __shared__ float dnpart[TTOK * 32];          // only e0/e1 use (DS<=32)
  __shared__ unsigned short dn[TTOK][136];
  __shared__ int toks[TTOK];
  int tid = threadIdx.x, wv = tid >> 6, lane = tid & 63;
  int w = blockIdx.x;
  const int* ts = cw + 8;
  if (w >= ts[4]) return;
  int e = (w >= ts[2]) ? ((w >= ts[3]) ? 3 : 2) : ((w >= ts[1]) ? 1 : 0);
  int tile = w - ts[e];
  int cnt = cw[e];
  if (e == 0)
    moe_body<0>(wv, lane, tid, tile, cnt, x, lists, wdT, wuT, bd0, bu0, out, dnpart, dn, toks);
  else if (e == 1)
    moe_body<1>(wv, lane, tid, tile, cnt, x, lists, wdT, wuT, bd1, bu1, out, dnpart, dn, toks);
  else if (e == 2)
    moe_body<2>(wv, lane, tid, tile, cnt, x, lists, wdT, wuT, bd2, bu2, out, dnpart, dn, toks);
  else
    moe_body<3>(wv, lane, tid, tile, cnt, x, lists, wdT, wuT, bd3, bu3, out, dnpart, dn, toks);
}

extern "C" void kernel_launch(void* const* d_in, const int* in_sizes, int n_in,
                              void* d_out, int out_size, void* d_ws, size_t ws_size,
                              hipStream_t stream) {
  const float* x = (const float*)d_in[0];
  const int* mask = (const int*)d_in[1];
  const float* Wd[4]; const float* bd[4]; const float* Wu[4]; const float* bu[4];
  for (int i = 0; i < 4; ++i) {
    Wd[i] = (const float*)d_in[2 + 4 * i];
    bd[i] = (const float*)d_in[3 + 4 * i];
    Wu[i] = (const float*)d_in[4 + 4 * i];
    bu[i] = (const float*)d_in[5 + 4 * i];
  }
  char* ws = (char*)d_ws;
  int* counts = (int*)ws;                                              // counts[4] + ts[5]
  int* lists = (int*)(ws + 256);                                       // 524288 B
  unsigned short* wdT = (unsigned short*)(ws + 256 + 524288);          // 368640 B
  unsigned short* wuT = (unsigned short*)(ws + 256 + 524288 + 368640); // 393216 B

  hipMemsetAsync(counts, 0, 64, stream);
  bucket_kernel<<<128, 256, 0, stream>>>(mask, counts, lists);
  prep_kernel<<<dim3(4, 32), 256, 0, stream>>>(Wd[0], Wd[1], Wd[2], Wd[3],
                                               Wu[0], Wu[1], Wu[2], Wu[3], wdT, wuT, counts);
  // one block per 16-token tile; at most 2048+3 tiles
  moe_main<<<2052, 256, 0, stream>>>(x, counts, lists, wdT, wuT,
                                     bd[0], bd[1], bd[2], bd[3],
                                     bu[0], bu[1], bu[2], bu[3],
                                     (float*)d_out);
}

// Round 4
// 106.882 us; speedup vs baseline: 3.6613x; 1.1322x over previous
//
#include <hip/hip_runtime.h>
#include <hip/hip_bf16.h>

#define DIM 768
#define NTOK 32768
#define TTOK 16

typedef __attribute__((ext_vector_type(8))) short short8;
typedef __attribute__((ext_vector_type(4))) float f32x4;

__device__ __forceinline__ unsigned short f2bf(float f) {
  union { float f; unsigned int u; } v; v.f = f;
  unsigned int u = v.u;
  return (unsigned short)((u + 0x7fffu + ((u >> 16) & 1u)) >> 16);
}
__device__ __forceinline__ float bf2f(unsigned short u) {
  union { unsigned int u; float f; } v; v.u = ((unsigned int)u) << 16; return v.f;
}

// ---- two-level bucketing: ballot rank -> LDS wave prefix -> 4 atomics/block
__global__ void bucket_kernel(const int* __restrict__ mask,
                              int* __restrict__ counts, int* __restrict__ lists) {
  int tid = threadIdx.x;
  int gid = blockIdx.x * 256 + tid;
  int wv = tid >> 6, lane = tid & 63;
  int e = mask[gid] & 3;
  __shared__ int wcnt[4][4];
  __shared__ int wbase[4][4];
  __shared__ int bbase[4];
  unsigned long long lt = (1ull << lane) - 1ull;
  int rank = 0;
  #pragma unroll
  for (int q = 0; q < 4; ++q) {
    unsigned long long m = __ballot(e == q);
    if (e == q) rank = __popcll(m & lt);
    if (lane == 0) wcnt[wv][q] = __popcll(m);
  }
  __syncthreads();
  if (tid < 4) {
    int s = 0;
    #pragma unroll
    for (int w2 = 0; w2 < 4; ++w2) { int c = wcnt[w2][tid]; wbase[w2][tid] = s; s += c; }
    bbase[tid] = atomicAdd(&counts[tid], s);
  }
  __syncthreads();
  int pos = bbase[e] + wbase[wv][e] + rank;
  lists[e * NTOK + pos] = gid;
}

// ---- weight repack to bf16 (WdT [ds][768], WuT [768][KP] zero-padded) + tileStart
__global__ void prep_kernel(const float* __restrict__ Wd0, const float* __restrict__ Wd1,
                            const float* __restrict__ Wd2, const float* __restrict__ Wd3,
                            const float* __restrict__ Wu0, const float* __restrict__ Wu1,
                            const float* __restrict__ Wu2, const float* __restrict__ Wu3,
                            unsigned short* __restrict__ wdT, unsigned short* __restrict__ wuT,
                            int* __restrict__ counts) {
  int e = blockIdx.x;
  int ds = 16 << e;
  int lgK = (e == 0) ? 5 : (4 + e);
  int KP = 1 << lgK;
  const float* Wd = (e == 0) ? Wd0 : (e == 1) ? Wd1 : (e == 2) ? Wd2 : Wd3;
  const float* Wu = (e == 0) ? Wu0 : (e == 1) ? Wu1 : (e == 2) ? Wu2 : Wu3;
  const int WOFF[4] = {0, 12288, 36864, 86016};
  const int UOFF[4] = {0, 24576, 49152, 98304};
  int stride = gridDim.y * 256;
  int start = blockIdx.y * 256 + threadIdx.x;
  int nd = ds * DIM;
  for (int i = start; i < nd; i += stride) {
    int k = i / DIM, d = i - k * DIM;
    wdT[WOFF[e] + i] = f2bf(Wd[d * ds + k]);
  }
  int nu = DIM << lgK;
  for (int i = start; i < nu; i += stride) {
    int dc = i >> lgK, k = i & (KP - 1);
    wuT[UOFF[e] + i] = (k < ds) ? f2bf(Wu[k * DIM + dc]) : (unsigned short)0;
  }
  if (e == 0 && blockIdx.y == 0 && threadIdx.x == 0) {
    int* ts = counts + 8;
    int s = 0;
    for (int q = 0; q < 4; ++q) { ts[q] = s; s += (counts[q] + 15) >> 4; }
    ts[4] = s;
  }
}

// Block-cooperative 16-token tile. All DRAM touches are row-bursts:
// stage-in x rows -> LDS bf16; MFMA phases read LDS/L2 only; results staged
// to LDS; stage-out does contiguous residual-read + store per row.
template <int E>
__device__ __forceinline__ void moe_body(
    int wv, int lane, int tid, int tile, int cnt,
    const float* __restrict__ x, const int* __restrict__ lists,
    const unsigned short* __restrict__ wdT, const unsigned short* __restrict__ wuT,
    const float* __restrict__ bd, const float* __restrict__ bu,
    float* __restrict__ out,
    unsigned short* xsol, float* dnpart, unsigned short (*dn)[136], int* toks) {
  constexpr int DS = 16 << E;
  constexpr int KP = (E == 0) ? 32 : DS;
  constexpr int NTA = DS / 16;
  constexpr int SPLIT_N = (NTA < 4) ? NTA : 4;   // 1,2,4,4
  constexpr int SPLIT_K = 4 / SPLIT_N;           // 4,2,1,1
  constexpr int NTB = NTA / SPLIT_N;             // 1,1,1,2
  constexpr int KLEN = DIM / SPLIT_K;            // 192,384,768,768
  constexpr int KB = KP / 32;                    // 1,1,2,4
  constexpr int WOFF[4] = {0, 12288, 36864, 86016};
  constexpr int UOFF[4] = {0, 24576, 49152, 98304};
  const unsigned short* wd = wdT + WOFF[E];
  const unsigned short* wu = wuT + UOFF[E];
  // xs: bf16 x tile, row stride 776 shorts (bank-group shift 1 -> 2-way max)
  // ol: bf16 out tile, row stride 772 shorts (overlaid on xs)
  #define XS(r) (xsol + (r) * 776)
  #define OL(r) (xsol + (r) * 772)

  int base = tile * TTOK;
  int lrow = lane & 15, kg = lane >> 4;
  if (tid < TTOK) toks[tid] = (base + tid < cnt) ? lists[E * NTOK + base + tid] : -1;
  if (SPLIT_K > 1) {
    for (int i = tid; i < TTOK * DS; i += 256) dnpart[i] = 0.f;
  }
  __syncthreads();

  // ---- stage-in: wave wv bursts rows wv*4..wv*4+3 (3x 1KB contiguous each)
  #pragma unroll
  for (int i = 0; i < 4; ++i) {
    int r = wv * 4 + i;
    int t = toks[r];
    const float* src = x + (size_t)((t >= 0) ? t : 0) * DIM;
    #pragma unroll
    for (int j = 0; j < 3; ++j) {
      int c = j * 256 + lane * 4;
      float4 v = {0.f, 0.f, 0.f, 0.f};
      if (t >= 0) v = *(const float4*)(src + c);
      ushort4 b;
      b.x = f2bf(v.x); b.y = f2bf(v.y); b.z = f2bf(v.z); b.w = f2bf(v.w);
      *(ushort4*)(XS(r) + c) = b;
    }
  }
  __syncthreads();

  // ---- phase A: dn = relu(X @ Wd + bd), A-frags from LDS
  int nsub = wv % SPLIT_N, ksub = wv / SPLIT_N;
  int d_base = ksub * KLEN;

  f32x4 acc[NTB];
  #pragma unroll
  for (int nb = 0; nb < NTB; ++nb) acc[nb] = f32x4{0.f, 0.f, 0.f, 0.f};

  for (int d0 = 0; d0 < KLEN; d0 += 64) {
    #pragma unroll
    for (int u = 0; u < 2; ++u) {
      int d = d_base + d0 + u * 32;
      short8 a = *(const short8*)(XS(lrow) + d + kg * 8);
      #pragma unroll
      for (int nb = 0; nb < NTB; ++nb) {
        int n = nsub * NTB + nb;
        short8 b = *(const short8*)(wd + (size_t)(n * 16 + lrow) * DIM + d + kg * 8);
        acc[nb] = __builtin_amdgcn_mfma_f32_16x16x32_bf16(a, b, acc[nb], 0, 0, 0);
      }
    }
  }

  if (SPLIT_K > 1) {
    #pragma unroll
    for (int nb = 0; nb < NTB; ++nb) {
      int kc = (nsub * NTB + nb) * 16 + lrow;
      #pragma unroll
      for (int r = 0; r < 4; ++r)
        atomicAdd(&dnpart[(kg * 4 + r) * DS + kc], acc[nb][r]);
    }
    __syncthreads();
    for (int i = tid; i < TTOK * KP; i += 256) {
      int tt = i / KP, k = i - tt * KP;
      float v = (k < DS) ? fmaxf(dnpart[tt * DS + k] + bd[k], 0.f) : 0.f;
      dn[tt][k] = f2bf(v);
    }
  } else {
    #pragma unroll
    for (int nb = 0; nb < NTB; ++nb) {
      int kc = (nsub * NTB + nb) * 16 + lrow;
      float bv = bd[kc];
      #pragma unroll
      for (int r = 0; r < 4; ++r)
        dn[kg * 4 + r][kc] = f2bf(fmaxf(acc[nb][r] + bv, 0.f));
    }
  }
  __syncthreads();

  // ---- phase B: up_partial = dn @ Wu + bu -> LDS out tile (bf16)
  short8 afr[KB];
  #pragma unroll
  for (int k = 0; k < KB; ++k) afr[k] = *(const short8*)&dn[lrow][k * 32 + kg * 8];

  #pragma unroll 3
  for (int nn = 0; nn < 12; ++nn) {
    int n = wv * 12 + nn;
    f32x4 c = {0.f, 0.f, 0.f, 0.f};
    #pragma unroll
    for (int k = 0; k < KB; ++k) {
      short8 b = *(const short8*)(wu + (size_t)(n * 16 + lrow) * KP + k * 32 + kg * 8);
      c = __builtin_amdgcn_mfma_f32_16x16x32_bf16(afr[k], b, c, 0, 0, 0);
    }
    int dcol = n * 16 + lrow;
    float bv = bu[dcol];
    #pragma unroll
    for (int r = 0; r < 4; ++r)
      OL(kg * 4 + r)[dcol] = f2bf(c[r] + bv);
  }
  __syncthreads();

  // ---- stage-out: wave wv bursts rows wv*4..wv*4+3: out = ol + x (residual)
  #pragma unroll
  for (int i = 0; i < 4; ++i) {
    int r = wv * 4 + i;
    int t = toks[r];
    if (t < 0) continue;
    const float* xsrc = x + (size_t)t * DIM;
    float* dst = out + (size_t)t * DIM;
    #pragma unroll
    for (int j = 0; j < 3; ++j) {
      int c = j * 256 + lane * 4;
      ushort4 ub = *(const ushort4*)(OL(r) + c);
      float4 xv = *(const float4*)(xsrc + c);
      float4 o;
      o.x = xv.x + bf2f(ub.x);
      o.y = xv.y + bf2f(ub.y);
      o.z = xv.z + bf2f(ub.z);
      o.w = xv.w + bf2f(ub.w);
      *(float4*)(dst + c) = o;
    }
  }
  #undef XS
  #undef OL
}

__global__ __launch_bounds__(256, 4) void moe_main(
    const float* __restrict__ x,
    const int* __restrict__ cw, const int* __restrict__ lists,
    const unsigned short* __restrict__ wdT, const unsigned short* __restrict__ wuT,
    const float* __restrict__ bd0, const float* __restrict__ bd1,
    const float* __restrict__ bd2, const float* __restrict__ bd3,
    const float* __restrict__ bu0, const float* __restrict__ bu1,
    const float* __restrict__ bu2, const float* __restrict__ bu3,
    float* __restrict__ out) {
  __shared__ unsigned short xsol[TTOK * 776];  // x tile / out tile (overlaid)
  __shared__ float dnpart[TTOK * 32];
  __shared__ unsigned short dn[TTOK][136];
  __shared__ int toks[TTOK];
  int tid = threadIdx.x, wv = tid >> 6, lane = tid & 63;
  int w = blockIdx.x;
  const int* ts = cw + 8;
  if (w >= ts[4]) return;
  int e = (w >= ts[2]) ? ((w >= ts[3]) ? 3 : 2) : ((w >= ts[1]) ? 1 : 0);
  int tile = w - ts[e];
  int cnt = cw[e];
  if (e == 0)
    moe_body<0>(wv, lane, tid, tile, cnt, x, lists, wdT, wuT, bd0, bu0, out, xsol, dnpart, dn, toks);
  else if (e == 1)
    moe_body<1>(wv, lane, tid, tile, cnt, x, lists, wdT, wuT, bd1, bu1, out, xsol, dnpart, dn, toks);
  else if (e == 2)
    moe_body<2>(wv, lane, tid, tile, cnt, x, lists, wdT, wuT, bd2, bu2, out, xsol, dnpart, dn, toks);
  else
    moe_body<3>(wv, lane, tid, tile, cnt, x, lists, wdT, wuT, bd3, bu3, out, xsol, dnpart, dn, toks);
}

extern "C" void kernel_launch(void* const* d_in, const int* in_sizes, int n_in,
                              void* d_out, int out_size, void* d_ws, size_t ws_size,
                              hipStream_t stream) {
  const float* x = (const float*)d_in[0];
  const int* mask = (const int*)d_in[1];
  const float* Wd[4]; const float* bd[4]; const float* Wu[4]; const float* bu[4];
  for (int i = 0; i < 4; ++i) {
    Wd[i] = (const float*)d_in[2 + 4 * i];
    bd[i] = (const float*)d_in[3 + 4 * i];
    Wu[i] = (const float*)d_in[4 + 4 * i];
    bu[i] = (const float*)d_in[5 + 4 * i];
  }
  char* ws = (char*)d_ws;
  int* counts = (int*)ws;                                              // counts[4] + ts[5]
  int* lists = (int*)(ws + 256);                                       // 524288 B
  unsigned short* wdT = (unsigned short*)(ws + 256 + 524288);          // 368640 B
  unsigned short* wuT = (unsigned short*)(ws + 256 + 524288 + 368640); // 393216 B

  hipMemsetAsync(counts, 0, 64, stream);
  bucket_kernel<<<128, 256, 0, stream>>>(mask, counts, lists);
  prep_kernel<<<dim3(4, 32), 256, 0, stream>>>(Wd[0], Wd[1], Wd[2], Wd[3],
                                               Wu[0], Wu[1], Wu[2], Wu[3], wdT, wuT, counts);
  moe_main<<<2052, 256, 0, stream>>>(x, counts, lists, wdT, wuT,
                                     bd[0], bd[1], bd[2], bd[3],
                                     bu[0], bu[1], bu[2], bu[3],
                                     (float*)d_out);
}